// Round 1
// baseline (320.401 us; speedup 1.0000x reference)
//
#include <hip/hip_runtime.h>

// Hidden-size-1 LSTM, B=32768 chains, 1024 open + 512 closed steps.
// R4: 4 lanes/chain (one gate per lane: 0=i, 1=f, 2=g, 3=o).
//  - Gate sigmoids for all 4 gates collapse into ONE ex2+rcp pair per
//    wave-step (was 2 pairs at 2 lanes/chain): per-step trans instrs 6->4,
//    total stream ~20 -> ~16. Trans issue (~12cyc/instr wave64) was ~70 of
//    the 110 issue cycles/step -> expect ~-30 cyc/step.
//  - quad_perm full broadcasts 0x00/0x55/0xAA/0xFF distribute ri,rf,rg,ro.
//  - 2048 waves = 2 waves/SIMD: staging/flush phases of co-resident waves
//    overlap; trans-pipe demand 2x~40cyc/step still fits under the wall.
//  - everything else (chunked LDS staging PAD=65, fused loss in flush,
//    pre-scaled C = 2*log2(e)*c, exp2/rcp sigmoid forms) unchanged from R3.
// sigma(z) = rcp(1+exp2(-L2E*z)); tanh(z) = 1 - 2*rcp(1+exp2(2*L2E*z)).

#define L2E 1.44269504088896340736f
#define B_TOT 32768
#define T_IN 1024
#define STEPS 512
#define CPB 16          // chains per block (one wave, 4 lanes/chain)
#define CH 64           // chunk length in steps
#define PAD 65          // LDS row stride: bank = (chain + s) % 32

__device__ __forceinline__ float ex2(float x){ return __builtin_amdgcn_exp2f(x); }
__device__ __forceinline__ float rcp(float x){ return __builtin_amdgcn_rcpf(x); }
template<int CTRL>
__device__ __forceinline__ float qp(float v){
    // quad_perm broadcast within each 4-lane chain group:
    // 0x00 -> all 4 lanes get lane0 (i), 0x55 -> lane1 (f),
    // 0xAA -> lane2 (g),               0xFF -> lane3 (o)
    return __int_as_float(__builtin_amdgcn_mov_dpp(__float_as_int(v), CTRL, 0xF, 0xF, true));
}

// per-lane gate constants: role = lane&3 (0=i, 1=f, 2=g, 3=o)
// i,f,o scaled by -L2E (sigma form); g scaled by +2*L2E (tanh form)
struct LaneK { float A, Bh, Cc, W; };

__device__ __forceinline__ void tail(float z, float& h, float& C){
    float e  = ex2(z);
    float r  = rcp(1.0f + e);
    float ri = qp<0x00>(r);       // sigma(zi)
    float rf = qp<0x55>(r);       // sigma(zf)
    float rg = qp<0xAA>(r);       // 1/(1+e^{2 zg})
    float ro = qp<0xFF>(r);       // sigma(zo)
    float g2 = fmaf(rg, -4.0f * L2E, 2.0f * L2E);   // 2*L2E*tanh(g)
    C = fmaf(rf, C, ri * g2);                        // C = 2*L2E*c_new
    float eC  = ex2(C);
    float ro2 = ro + ro;          // parallel with the rcp below
    float rc  = rcp(1.0f + eC);
    h = fmaf(-rc, ro2, ro);       // h = ro*(1-2rc)
}

// stage a 16-row x 64-col chunk: 4 float4/lane, coalesced global reads
// (16 lanes cover one full 256B row per j: same coalescing as the R3 stager)
__device__ __forceinline__ void stage_issue16(const float* __restrict__ base,
                                              int rs, int col0, int lane, float4* v){
    const int r_lo = lane >> 4, c4 = lane & 15;     // r_lo 0..3, c4 0..15
    #pragma unroll
    for (int j = 0; j < 4; ++j)
        v[j] = *(const float4*)(base + (size_t)(j*4 + r_lo) * rs + col0 + c4*4);
}
__device__ __forceinline__ void stage_write16(float* __restrict__ lds, int lane,
                                              const float4* v){
    const int r_lo = lane >> 4, c4 = lane & 15;
    #pragma unroll
    for (int j = 0; j < 4; ++j){
        float* p = lds + (j*4 + r_lo) * PAD + c4*4;   // rows 4B-aligned (PAD=65)
        p[0]=v[j].x; p[1]=v[j].y; p[2]=v[j].z; p[3]=v[j].w;
    }
}

__global__ __launch_bounds__(64) void lstm_chain_kernel(
    const float* __restrict__ x, const float* __restrict__ t,
    const float* __restrict__ h0, const float* __restrict__ c0,
    const float* __restrict__ w_ih, const float* __restrict__ w_hh,
    const float* __restrict__ b_ih, const float* __restrict__ b_hh,
    float* __restrict__ out)
{
    __shared__ float sb[2][CPB * PAD];   // x/t staging, double-buffered
    __shared__ float pb[CPB * PAD];      // pred staging

    const int lane = threadIdx.x;
    const int role = lane & 3;           // 0=i 1=f 2=g 3=o
    const int ch   = lane >> 2;          // chain within block (0..15)
    const int b0   = blockIdx.x * CPB;

    LaneK K;
    {
        float wih = w_ih[role], whh = w_hh[role];
        float bb  = b_ih[role] + b_hh[role];
        float sc  = (role == 2) ? (2.0f * L2E) : (-L2E);
        K.A  = sc * wih;
        K.Bh = sc * whh;
        K.Cc = sc * bb;
        K.W  = K.A + K.Bh;               // closed loop: x_in = h
    }

    float h = h0[b0 + ch];
    float C = (2.0f * L2E) * c0[b0 + ch];

    const float* xbase = x + (size_t)b0 * T_IN;
    const float* tbase = t + (size_t)b0 * STEPS;

    // ---- open loop: 16 chunks of 64 steps ----
    { float4 stg[4]; stage_issue16(xbase, T_IN, 0, lane, stg); stage_write16(sb[0], lane, stg); }
    #pragma unroll 1
    for (int k = 0; k < T_IN / CH; ++k){
        float4 stg[4];
        if (k < T_IN/CH - 1) stage_issue16(xbase, T_IN, (k+1)*CH, lane, stg);
        const float* xrow = &sb[k & 1][ch * PAD];
        #pragma unroll 8
        for (int s = 0; s < CH; ++s){
            float xv = xrow[s];
            // x-side FMA off the h-critical path
            float z = fmaf(h, K.Bh, fmaf(xv, K.A, K.Cc));
            tail(z, h, C);
        }
        if (k < T_IN/CH - 1) stage_write16(sb[(k+1) & 1], lane, stg);
    }
    float xin = sb[1][ch * PAD + (CH - 1)];   // x[b,1023] (chunk 15 -> buf 1)

    // ---- closed loop: 8 chunks of 64 steps ----
    { float4 stg[4]; stage_issue16(tbase, STEPS, 0, lane, stg); stage_write16(sb[0], lane, stg); }
    float lacc = 0.0f;
    #pragma unroll 1
    for (int k = 0; k < STEPS / CH; ++k){
        float4 stg[4];
        if (k < STEPS/CH - 1) stage_issue16(tbase, STEPS, (k+1)*CH, lane, stg);
        float* prow = &pb[ch * PAD];
        if (k == 0){
            // first closed step feeds x[b,1023], not h
            tail(fmaf(h, K.Bh, fmaf(xin, K.A, K.Cc)), h, C);
            prow[0] = h;
            #pragma unroll 8
            for (int s = 1; s < CH; ++s){
                tail(fmaf(h, K.W, K.Cc), h, C);
                prow[s] = h;
            }
        } else {
            #pragma unroll 8
            for (int s = 0; s < CH; ++s){
                tail(fmaf(h, K.W, K.Cc), h, C);
                prow[s] = h;
            }
        }
        // flush + fused loss: coalesced LDS reads (bank = (r+lane)%32),
        // 64 consecutive dwords per global store instruction
        const float* trow = &sb[k & 1][0];
        float* obase = out + 1 + (size_t)b0 * STEPS + k * CH;
        #pragma unroll 4
        for (int r = 0; r < CPB; ++r){
            float p  = pb[r * PAD + lane];
            float tv = trow[r * PAD + lane];
            float d  = p - tv;
            lacc = fmaf(d, d, lacc);
            obase[(size_t)r * STEPS + lane] = p;
        }
        if (k < STEPS/CH - 1) stage_write16(sb[(k+1) & 1], lane, stg);
    }

    // ---- loss: each (chain, step) counted exactly once -> scale 1/B ----
    #pragma unroll
    for (int off = 32; off > 0; off >>= 1)
        lacc += __shfl_down(lacc, off, 64);
    if (lane == 0)
        atomicAdd(out, lacc * (1.0f / (float)B_TOT));
}

extern "C" void kernel_launch(void* const* d_in, const int* in_sizes, int n_in,
                              void* d_out, int out_size, void* d_ws, size_t ws_size,
                              hipStream_t stream) {
    const float* x    = (const float*)d_in[0];
    const float* t    = (const float*)d_in[1];
    const float* h0   = (const float*)d_in[2];
    const float* c0   = (const float*)d_in[3];
    const float* w_ih = (const float*)d_in[4];
    const float* w_hh = (const float*)d_in[5];
    const float* b_ih = (const float*)d_in[6];
    const float* b_hh = (const float*)d_in[7];
    float* out = (float*)d_out;

    hipMemsetAsync(out, 0, sizeof(float), stream);

    lstm_chain_kernel<<<B_TOT / CPB, 64, 0, stream>>>(
        x, t, h0, c0, w_ih, w_hh, b_ih, b_hh, out);
}